// Round 4
// baseline (1076.677 us; speedup 1.0000x reference)
//
#include <hip/hip_runtime.h>
#include <cstdint>
#include <cstddef>

#define B_DIM 16
#define N_DIM 2048
#define BN (B_DIM * N_DIM)          // 32768 rows per modality
#define QSCALE 0.18033688f          // 0.125 * log2(e): P = exp2(S')
#define PLANE ((size_t)BN * 64)     // elems per (jj,i) partial plane
#define MBPLANE ((size_t)N_DIM * 64) // elems per (modality,batch) tensor block

typedef __attribute__((ext_vector_type(4))) float f32x4;
typedef __attribute__((ext_vector_type(2))) float f32x2;
typedef __attribute__((ext_vector_type(16))) float f32x16;
typedef __attribute__((ext_vector_type(8))) __bf16 bf16x8;
typedef __attribute__((ext_vector_type(2))) unsigned int u32x2;

__device__ __forceinline__ unsigned short f2bf_rne(float f) {
    union { float f; unsigned int u; } v; v.f = f;
    unsigned int u = v.u;
    return (unsigned short)((u + 0x7fffu + ((u >> 16) & 1u)) >> 16);
}
__device__ __forceinline__ unsigned pk_rne(float a, float b) {
    return (unsigned)f2bf_rne(a) | ((unsigned)f2bf_rne(b) << 16);
}
// half_swap(a,b): res.x = {a.lo32, b.lo32}, res.y = {a.hi32, b.hi32}
__device__ __forceinline__ u32x2 half_swap(unsigned a, unsigned b) {
#if __has_builtin(__builtin_amdgcn_permlane32_swap)
    return __builtin_amdgcn_permlane32_swap(a, b, false, false);
#else
    unsigned pa = (unsigned)__shfl_xor((int)a, 32);
    unsigned pb = (unsigned)__shfl_xor((int)b, 32);
    bool hi = (threadIdx.x & 32) != 0;
    u32x2 r;
    r.x = hi ? pb : a;
    r.y = hi ? b : pa;
    return r;
#endif
}

// async global->LDS, 16B per lane; LDS dest = wave-uniform base + lane*16
__device__ __forceinline__ void g2lds16(const unsigned short* g, unsigned short* ldsbase) {
#if __has_builtin(__builtin_amdgcn_global_load_lds)
    __builtin_amdgcn_global_load_lds(
        (const __attribute__((address_space(1))) unsigned int*)g,
        (__attribute__((address_space(3))) unsigned int*)ldsbase,
        16, 0, 0);
#else
    int ln = threadIdx.x & 63;
    *(uint4*)(ldsbase + ln * 8) = *(const uint4*)g;
#endif
}

// ---------------------------------------------------------------------------
// prep (MFMA): Q = (x@W)*QSCALE, K = x@W^T, V = x^T — all emitted in TILED
// slab layouts (R0-verified):
//   Q: [m][b][g=q/64][qi=(q>>5)&1][chunk 0..7][lq=q&31][8elem]
//   K: [m][b][kt=key/64][chunk 0..7][key&63][8elem]      (chunk = d/8)
//   V: [m][b][kt][chunk=keygrp 0..7][d 0..63][8 keys]    (x^T slabs)
// ---------------------------------------------------------------------------
__global__ __launch_bounds__(256) void prep_kernel(
    const float* __restrict__ x0, const float* __restrict__ x1, const float* __restrict__ x2,
    const float* __restrict__ w0, const float* __restrict__ w1, const float* __restrict__ w2,
    unsigned short* __restrict__ Qbf, unsigned short* __restrict__ Kbf,
    unsigned short* __restrict__ Vt)
{
    __shared__ float Wf[64 * 64];
    __shared__ float xs[128 * 68];

    int m    = blockIdx.x >> 8;
    int tile = blockIdx.x & 255;
    int row0 = tile * 128;
    int b    = row0 >> 11;
    int n0   = row0 & 2047;
    const float* x = (m == 0) ? x0 : (m == 1) ? x1 : x2;
    const float* W = (m == 0) ? w0 : (m == 1) ? w1 : w2;
    int tid = threadIdx.x;

    #pragma unroll
    for (int v = 0; v < 4; ++v) {
        int i4 = v * 256 + tid;
        *(f32x4*)&Wf[i4 * 4] = *(const f32x4*)&W[i4 * 4];
    }
    #pragma unroll
    for (int v = 0; v < 8; ++v) {
        int i4 = v * 256 + tid;
        int r = i4 >> 4, c = (i4 & 15) * 4;
        *(f32x4*)&xs[r * 68 + c] = *(const f32x4*)&x[(size_t)row0 * 64 + i4 * 4];
    }
    __syncthreads();

    int lane = tid & 63, wave = tid >> 6, lq = lane & 31, h = lane >> 5;

    bf16x8 wq[2][4], wk[2][4];
    #pragma unroll
    for (int mf = 0; mf < 2; ++mf)
        #pragma unroll
        for (int kc = 0; kc < 4; ++kc) {
            int e  = mf * 32 + lq;
            int d0 = kc * 16 + h * 8;
            unsigned uq[4], uk[4];
            #pragma unroll
            for (int t = 0; t < 4; ++t) {
                int d = d0 + 2 * t;
                uq[t] = pk_rne(Wf[d * 64 + e] * QSCALE, Wf[(d + 1) * 64 + e] * QSCALE);
                uk[t] = pk_rne(Wf[e * 64 + d], Wf[e * 64 + d + 1]);
            }
            uint4 ua; ua.x = uq[0]; ua.y = uq[1]; ua.z = uq[2]; ua.w = uq[3];
            uint4 ub; ub.x = uk[0]; ub.y = uk[1]; ub.z = uk[2]; ub.w = uk[3];
            wq[mf][kc] = __builtin_bit_cast(bf16x8, ua);
            wk[mf][kc] = __builtin_bit_cast(bf16x8, ub);
        }

    bf16x8 xb[4];
    #pragma unroll
    for (int kc = 0; kc < 4; ++kc) {
        const float* xr = &xs[(wave * 32 + lq) * 68 + kc * 16 + h * 8];
        unsigned u[4];
        #pragma unroll
        for (int t = 0; t < 4; ++t) u[t] = pk_rne(xr[2 * t], xr[2 * t + 1]);
        uint4 ua; ua.x = u[0]; ua.y = u[1]; ua.z = u[2]; ua.w = u[3];
        xb[kc] = __builtin_bit_cast(bf16x8, ua);
    }

    f32x16 Qt[2], Kt[2];
    #pragma unroll
    for (int r = 0; r < 16; ++r) { Qt[0][r] = 0.f; Qt[1][r] = 0.f; Kt[0][r] = 0.f; Kt[1][r] = 0.f; }
    #pragma unroll
    for (int kc = 0; kc < 4; ++kc) {
        #pragma unroll
        for (int mf = 0; mf < 2; ++mf) {
            Qt[mf] = __builtin_amdgcn_mfma_f32_32x32x16_bf16(wq[mf][kc], xb[kc], Qt[mf], 0, 0, 0);
            Kt[mf] = __builtin_amdgcn_mfma_f32_32x32x16_bf16(wk[mf][kc], xb[kc], Kt[mf], 0, 0, 0);
        }
    }

    // ---- tiled stores -------------------------------------------------------
    size_t mbBase = ((size_t)m * B_DIM + b) * MBPLANE;
    int nn  = n0 + wave * 32 + lq;        // q/key index within (m,b)
    int g   = nn >> 6;                    // 64-row group
    int qi  = (nn >> 5) & 1;
    int ktp = nn >> 6, keyp = nn & 63;
    unsigned short* qb = Qbf + mbBase + (size_t)(g * 2 + qi) * 2048 + lq * 8;   // + c*256
    unsigned short* kb = Kbf + mbBase + (size_t)ktp * 4096 + keyp * 8;          // + c*512

    #pragma unroll
    for (int s = 0; s < 4; ++s) {
        int c = 4 * h + s;                // elem-chunk index (d-chunk)
        unsigned q00 = pk_rne(Qt[0][4 * s], Qt[0][4 * s + 1]);
        unsigned q01 = pk_rne(Qt[0][4 * s + 2], Qt[0][4 * s + 3]);
        unsigned q10 = pk_rne(Qt[1][4 * s], Qt[1][4 * s + 1]);
        unsigned q11 = pk_rne(Qt[1][4 * s + 2], Qt[1][4 * s + 3]);
        u32x2 a = half_swap(q00, q10);
        u32x2 cc = half_swap(q01, q11);
        uint4 w; w.x = a.x; w.y = cc.x; w.z = a.y; w.w = cc.y;
        *(uint4*)&qb[c * 256] = w;

        unsigned k00 = pk_rne(Kt[0][4 * s], Kt[0][4 * s + 1]);
        unsigned k01 = pk_rne(Kt[0][4 * s + 2], Kt[0][4 * s + 3]);
        unsigned k10 = pk_rne(Kt[1][4 * s], Kt[1][4 * s + 1]);
        unsigned k11 = pk_rne(Kt[1][4 * s + 2], Kt[1][4 * s + 3]);
        u32x2 a2 = half_swap(k00, k10);
        u32x2 c2 = half_swap(k01, k11);
        uint4 w2; w2.x = a2.x; w2.y = c2.x; w2.z = a2.y; w2.w = c2.y;
        *(uint4*)&kb[c * 512] = w2;
    }

    // V slabs: thread owns d = tid&63, key-range ng*32..+32
    int d  = tid & 63;
    int ng = tid >> 6;
    #pragma unroll
    for (int s = 0; s < 4; ++s) {
        int keystart = n0 + ng * 32 + 8 * s;
        int ktv = keystart >> 6;
        int cv  = (keystart & 63) >> 3;
        uint4 w;
        int rb = ng * 32 + 8 * s;
        w.x = pk_rne(xs[(rb + 0) * 68 + d], xs[(rb + 1) * 68 + d]);
        w.y = pk_rne(xs[(rb + 2) * 68 + d], xs[(rb + 3) * 68 + d]);
        w.z = pk_rne(xs[(rb + 4) * 68 + d], xs[(rb + 5) * 68 + d]);
        w.w = pk_rne(xs[(rb + 6) * 68 + d], xs[(rb + 7) * 68 + d]);
        *(uint4*)&Vt[mbBase + (size_t)(ktv * 8 + cv) * 512 + d * 8] = w;
    }
}

// ---------------------------------------------------------------------------
// attention: DOUBLE-buffered 64-key tiles (32 KB LDS -> 5 blocks/CU,
// 20 waves/CU; was 3 blocks at 48 KB). Legality of 2 buffers comes from
// reordering the kf==0 iteration: exp(g-1) -> PV(g-1) -> barrier ->
// stage(kt+1) -> QK(g). All reads of the buffer being overwritten complete
// before the barrier (syncthreads drains lgkmcnt+vmcnt); the stage DMA into
// that buffer is only consumed after the NEXT barrier drains it.
// ---------------------------------------------------------------------------
__global__ __launch_bounds__(256, 5) void attn_kernel(
    const unsigned short* __restrict__ Qbf,
    const unsigned short* __restrict__ Kbf,
    const unsigned short* __restrict__ Vt,
    unsigned short* __restrict__ part)
{
    __shared__ unsigned short Ks[2][4096];   // 8 slabs x [key 0..63][8elem]
    __shared__ unsigned short Vs[2][4096];   // 8 slabs x [d 0..63][8 keys]

    int blk = blockIdx.x;                    // 1536 = 6 pairs * 16 b * 16 qt
    int qt  = blk & 15;
    int b   = (blk >> 4) & 15;
    int p   = blk >> 8;
    int i   = p >> 1, jj = p & 1;
    int j   = i + 1 + jj; if (j >= 3) j -= 3;

    int tid = threadIdx.x, wave = tid >> 6, lane = tid & 63;
    int lq = lane & 31, h = lane >> 5;

    const unsigned short* KgT = Kbf + ((size_t)j * B_DIM + b) * MBPLANE;
    const unsigned short* VgT = Vt  + ((size_t)j * B_DIM + b) * MBPLANE;
    const unsigned short* QgT = Qbf + ((size_t)i * B_DIM + b) * MBPLANE;

    // wave stages slabs {2w, 2w+1} of K and V; global side contiguous 1KB
    int c0 = wave * 2;
    auto stage = [&](int buf, int kt) {
        const unsigned short* gk = KgT + ((size_t)(kt * 8 + c0) * 64 + lane) * 8;
        const unsigned short* gv = VgT + ((size_t)(kt * 8 + c0) * 64 + lane) * 8;
        g2lds16(gk,       &Ks[buf][c0 * 512]);
        g2lds16(gk + 512, &Ks[buf][c0 * 512 + 512]);
        g2lds16(gv,       &Vs[buf][c0 * 512]);
        g2lds16(gv + 512, &Vs[buf][c0 * 512 + 512]);
    };

    // prologue: stage tiles 0 and 1
    stage(0, 0);
    stage(1, 1);

    // Q B-frags (wave owns 32 queries: n = qt*128 + wave*32)
    int gq  = qt * 2 + (wave >> 1);
    int qih = wave & 1;
    bf16x8 qf[4];
    #pragma unroll
    for (int kc = 0; kc < 4; ++kc)
        qf[kc] = __builtin_bit_cast(bf16x8, *(const uint4*)&QgT[
            (size_t)(gq * 2 + qih) * 2048 + (kc * 2 + h) * 256 + lq * 8]);

    f32x16 O[2];                             // [df]
    #pragma unroll
    for (int r = 0; r < 16; ++r) { O[0][r] = 0.f; O[1][r] = 0.f; }
    f32x2 ls2; ls2.x = 0.f; ls2.y = 0.f;

    __syncthreads();    // publishes tiles 0,1

    // pipeline prime: QK of stage g=0 (tile 0, kf 0)
    f32x16 st;
    {
        const unsigned short* Kb = Ks[0];
        bf16x8 kfr[4];
        #pragma unroll
        for (int kc = 0; kc < 4; ++kc)
            kfr[kc] = __builtin_bit_cast(bf16x8,
                *(const uint4*)&Kb[(2 * kc + h) * 512 + lq * 8]);
        f32x16 acc;
        #pragma unroll
        for (int r = 0; r < 16; ++r) acc[r] = 0.f;
        #pragma unroll
        for (int kc = 0; kc < 4; ++kc)
            acc = __builtin_amdgcn_mfma_f32_32x32x16_bf16(kfr[kc], qf[kc], acc, 0, 0, 0);
        st = acc;
    }

    for (int g = 1; g < 64; ++g) {
        int kt = g >> 1, kf = g & 1;

        // ---- exp/pack of stage g-1 (scores ready since last iteration) ----
        unsigned pkk[4][2];
        #pragma unroll
        for (int s = 0; s < 4; ++s) {
            float e0 = __builtin_amdgcn_exp2f(st[4 * s + 0]);
            float e1 = __builtin_amdgcn_exp2f(st[4 * s + 1]);
            float e2 = __builtin_amdgcn_exp2f(st[4 * s + 2]);
            float e3 = __builtin_amdgcn_exp2f(st[4 * s + 3]);
            f32x2 p01; p01.x = e0; p01.y = e1;
            f32x2 p23; p23.x = e2; p23.y = e3;
            ls2 += p01;                      // v_pk_add_f32
            ls2 += p23;
            pkk[s][0] = __builtin_amdgcn_perm(
                __builtin_bit_cast(unsigned, e1), __builtin_bit_cast(unsigned, e0), 0x07060302u);
            pkk[s][1] = __builtin_amdgcn_perm(
                __builtin_bit_cast(unsigned, e3), __builtin_bit_cast(unsigned, e2), 0x07060302u);
        }

        // P fragments of stage g-1
        int kfp = (g - 1) & 1;
        bf16x8 pf[2];
        #pragma unroll
        for (int c = 0; c < 2; ++c) {
            u32x2 rr0 = half_swap(pkk[2 * c][0], pkk[2 * c + 1][0]);
            u32x2 rr1 = half_swap(pkk[2 * c][1], pkk[2 * c + 1][1]);
            uint4 t; t.x = rr0.x; t.y = rr1.x; t.z = rr0.y; t.w = rr1.y;
            pf[c] = __builtin_bit_cast(bf16x8, t);
        }
        const unsigned short* Vb = Vs[((g - 1) >> 1) & 1];

        if (kf == 0) {
            // ---- PV of stage g-1 BEFORE the barrier (reads V tile kt-1) ----
            #pragma unroll
            for (int c = 0; c < 2; ++c) {
                int kcpv = 2 * kfp + c;
                #pragma unroll
                for (int df = 0; df < 2; ++df) {
                    bf16x8 vfr = __builtin_bit_cast(bf16x8,
                        *(const uint4*)&Vb[(2 * kcpv + h) * 512 + (df * 32 + lq) * 8]);
                    O[df] = __builtin_amdgcn_mfma_f32_32x32x16_bf16(vfr, pf[c], O[df], 0, 0, 0);
                }
            }
            __syncthreads();                 // publish tile kt; all reads of buf (kt+1)&1 done
            if (kt < 31) stage((kt + 1) & 1, kt + 1);
            // ---- QK of stage g ----
            {
                const unsigned short* Kb = Ks[kt & 1];
                bf16x8 kfr[4];
                #pragma unroll
                for (int kc = 0; kc < 4; ++kc)
                    kfr[kc] = __builtin_bit_cast(bf16x8,
                        *(const uint4*)&Kb[(2 * kc + h) * 512 + (kf * 32 + lq) * 8]);
                f32x16 acc;
                #pragma unroll
                for (int r = 0; r < 16; ++r) acc[r] = 0.f;
                #pragma unroll
                for (int kc = 0; kc < 4; ++kc)
                    acc = __builtin_amdgcn_mfma_f32_32x32x16_bf16(kfr[kc], qf[kc], acc, 0, 0, 0);
                st = acc;
            }
        } else {
            // ---- QK of stage g (same tile, no barrier) ----
            {
                const unsigned short* Kb = Ks[kt & 1];
                bf16x8 kfr[4];
                #pragma unroll
                for (int kc = 0; kc < 4; ++kc)
                    kfr[kc] = __builtin_bit_cast(bf16x8,
                        *(const uint4*)&Kb[(2 * kc + h) * 512 + (kf * 32 + lq) * 8]);
                f32x16 acc;
                #pragma unroll
                for (int r = 0; r < 16; ++r) acc[r] = 0.f;
                #pragma unroll
                for (int kc = 0; kc < 4; ++kc)
                    acc = __builtin_amdgcn_mfma_f32_32x32x16_bf16(kfr[kc], qf[kc], acc, 0, 0, 0);
                st = acc;
            }
            // ---- PV of stage g-1 ----
            #pragma unroll
            for (int c = 0; c < 2; ++c) {
                int kcpv = 2 * kfp + c;
                #pragma unroll
                for (int df = 0; df < 2; ++df) {
                    bf16x8 vfr = __builtin_bit_cast(bf16x8,
                        *(const uint4*)&Vb[(2 * kcpv + h) * 512 + (df * 32 + lq) * 8]);
                    O[df] = __builtin_amdgcn_mfma_f32_32x32x16_bf16(vfr, pf[c], O[df], 0, 0, 0);
                }
            }
        }
    }

    // ---- drain: exp/pack + PV of last stage (tile 31, kf 1, buf 1) ----
    {
        unsigned pkk[4][2];
        #pragma unroll
        for (int s = 0; s < 4; ++s) {
            float e0 = __builtin_amdgcn_exp2f(st[4 * s + 0]);
            float e1 = __builtin_amdgcn_exp2f(st[4 * s + 1]);
            float e2 = __builtin_amdgcn_exp2f(st[4 * s + 2]);
            float e3 = __builtin_amdgcn_exp2f(st[4 * s + 3]);
            f32x2 p01; p01.x = e0; p01.y = e1;
            f32x2 p23; p23.x = e2; p23.y = e3;
            ls2 += p01;
            ls2 += p23;
            pkk[s][0] = __builtin_amdgcn_perm(
                __builtin_bit_cast(unsigned, e1), __builtin_bit_cast(unsigned, e0), 0x07060302u);
            pkk[s][1] = __builtin_amdgcn_perm(
                __builtin_bit_cast(unsigned, e3), __builtin_bit_cast(unsigned, e2), 0x07060302u);
        }
        const unsigned short* Vb = Vs[1];
        #pragma unroll
        for (int c = 0; c < 2; ++c) {
            u32x2 rr0 = half_swap(pkk[2 * c][0], pkk[2 * c + 1][0]);
            u32x2 rr1 = half_swap(pkk[2 * c][1], pkk[2 * c + 1][1]);
            uint4 t; t.x = rr0.x; t.y = rr1.x; t.z = rr0.y; t.w = rr1.y;
            bf16x8 pf = __builtin_bit_cast(bf16x8, t);
            int kcpv = 2 * 1 + c;
            #pragma unroll
            for (int df = 0; df < 2; ++df) {
                bf16x8 vfr = __builtin_bit_cast(bf16x8,
                    *(const uint4*)&Vb[(2 * kcpv + h) * 512 + (df * 32 + lq) * 8]);
                O[df] = __builtin_amdgcn_mfma_f32_32x32x16_bf16(vfr, pf, O[df], 0, 0, 0);
            }
        }
    }

    // epilogue: normalize, half-swap to row layout, store bf16 partial rows
    {
        float l = ls2.x + ls2.y;
        l += __shfl_xor(l, 32);
        float inv = 1.0f / l;
        #pragma unroll
        for (int r = 0; r < 16; ++r) { O[0][r] *= inv; O[1][r] *= inv; }

        unsigned short* dst = part + ((size_t)jj * 3 + i) * PLANE
            + (size_t)(b * N_DIM + qt * 128 + wave * 32 + lq) * 64 + h * 32;
        #pragma unroll
        for (int s = 0; s < 4; ++s) {
            unsigned t00 = pk_rne(O[0][4 * s], O[0][4 * s + 1]);
            unsigned t01 = pk_rne(O[0][4 * s + 2], O[0][4 * s + 3]);
            unsigned t10 = pk_rne(O[1][4 * s], O[1][4 * s + 1]);
            unsigned t11 = pk_rne(O[1][4 * s + 2], O[1][4 * s + 3]);
            u32x2 a = half_swap(t00, t10);
            u32x2 c = half_swap(t01, t11);
            uint4 w; w.x = a.x; w.y = c.x; w.z = a.y; w.w = c.y;
            *(uint4*)&dst[s * 8] = w;
        }
    }
}

// ---------------------------------------------------------------------------
// reduce: out = (1/3) * sum of 6 bf16 partial planes
// ---------------------------------------------------------------------------
__global__ __launch_bounds__(256) void reduce_kernel(
    const unsigned short* __restrict__ part, float* __restrict__ out)
{
    size_t e = ((size_t)blockIdx.x * 256 + threadIdx.x) * 4;
    float a0 = 0.f, a1 = 0.f, a2 = 0.f, a3 = 0.f;
    #pragma unroll
    for (int q = 0; q < 6; ++q) {
        const unsigned short* pp = part + (size_t)q * PLANE + e;
        unsigned u0 = *(const unsigned*)&pp[0];
        unsigned u1 = *(const unsigned*)&pp[2];
        a0 += __builtin_bit_cast(float, u0 << 16);
        a1 += __builtin_bit_cast(float, u0 & 0xffff0000u);
        a2 += __builtin_bit_cast(float, u1 << 16);
        a3 += __builtin_bit_cast(float, u1 & 0xffff0000u);
    }
    f32x4 v;
    v.x = a0 * (1.0f / 3.0f); v.y = a1 * (1.0f / 3.0f);
    v.z = a2 * (1.0f / 3.0f); v.w = a3 * (1.0f / 3.0f);
    *(f32x4*)&out[e] = v;
}

extern "C" void kernel_launch(void* const* d_in, const int* in_sizes, int n_in,
                              void* d_out, int out_size, void* d_ws, size_t ws_size,
                              hipStream_t stream)
{
    const float* x0 = (const float*)d_in[0];
    const float* x1 = (const float*)d_in[1];
    const float* x2 = (const float*)d_in[2];
    const float* w0 = (const float*)d_in[3];
    const float* w1 = (const float*)d_in[4];
    const float* w2 = (const float*)d_in[5];
    float* out = (float*)d_out;

    size_t nElem = (size_t)3 * BN * 64;
    unsigned short* Qbf = (unsigned short*)d_ws;
    unsigned short* Kbf = Qbf + nElem;
    unsigned short* Vt  = Kbf + nElem;
    unsigned short* part = Vt + nElem;      // 6 planes * BN*64 bf16

    hipLaunchKernelGGL(prep_kernel, dim3(3 * (BN / 128)), dim3(256), 0, stream,
                       x0, x1, x2, w0, w1, w2, Qbf, Kbf, Vt);
    hipLaunchKernelGGL(attn_kernel, dim3(6 * B_DIM * (N_DIM / 128)), dim3(256), 0, stream,
                       Qbf, Kbf, Vt, part);
    hipLaunchKernelGGL(reduce_kernel, dim3((BN * 64 / 4) / 256), dim3(256), 0, stream,
                       part, out);
}

// Round 5
// 208.550 us; speedup vs baseline: 5.1627x; 5.1627x over previous
//
#include <hip/hip_runtime.h>
#include <cstdint>
#include <cstddef>

#define B_DIM 16
#define N_DIM 2048
#define BN (B_DIM * N_DIM)          // 32768 rows per modality
#define QSCALE 0.18033688f          // 0.125 * log2(e): P = exp2(S')
#define PLANE ((size_t)BN * 64)     // elems per (jj,i) partial plane
#define MBPLANE ((size_t)N_DIM * 64) // elems per (modality,batch) tensor block

typedef __attribute__((ext_vector_type(4))) float f32x4;
typedef __attribute__((ext_vector_type(2))) float f32x2;
typedef __attribute__((ext_vector_type(16))) float f32x16;
typedef __attribute__((ext_vector_type(8))) __bf16 bf16x8;
typedef __attribute__((ext_vector_type(2))) unsigned int u32x2;

__device__ __forceinline__ unsigned short f2bf_rne(float f) {
    union { float f; unsigned int u; } v; v.f = f;
    unsigned int u = v.u;
    return (unsigned short)((u + 0x7fffu + ((u >> 16) & 1u)) >> 16);
}
__device__ __forceinline__ unsigned pk_rne(float a, float b) {
    return (unsigned)f2bf_rne(a) | ((unsigned)f2bf_rne(b) << 16);
}
// half_swap(a,b): res.x = {a.lo32, b.lo32}, res.y = {a.hi32, b.hi32}
__device__ __forceinline__ u32x2 half_swap(unsigned a, unsigned b) {
#if __has_builtin(__builtin_amdgcn_permlane32_swap)
    return __builtin_amdgcn_permlane32_swap(a, b, false, false);
#else
    unsigned pa = (unsigned)__shfl_xor((int)a, 32);
    unsigned pb = (unsigned)__shfl_xor((int)b, 32);
    bool hi = (threadIdx.x & 32) != 0;
    u32x2 r;
    r.x = hi ? pb : a;
    r.y = hi ? b : pa;
    return r;
#endif
}

// async global->LDS, 16B per lane; LDS dest = wave-uniform base + lane*16
__device__ __forceinline__ void g2lds16(const unsigned short* g, unsigned short* ldsbase) {
#if __has_builtin(__builtin_amdgcn_global_load_lds)
    __builtin_amdgcn_global_load_lds(
        (const __attribute__((address_space(1))) unsigned int*)g,
        (__attribute__((address_space(3))) unsigned int*)ldsbase,
        16, 0, 0);
#else
    int ln = threadIdx.x & 63;
    *(uint4*)(ldsbase + ln * 8) = *(const uint4*)g;
#endif
}

// ---------------------------------------------------------------------------
// prep (MFMA): Q = (x@W)*QSCALE, K = x@W^T, V = x^T — all emitted in TILED
// slab layouts (R0-verified):
//   Q: [m][b][g=q/64][qi=(q>>5)&1][chunk 0..7][lq=q&31][8elem]
//   K: [m][b][kt=key/64][chunk 0..7][key&63][8elem]      (chunk = d/8)
//   V: [m][b][kt][chunk=keygrp 0..7][d 0..63][8 keys]    (x^T slabs)
// ---------------------------------------------------------------------------
__global__ __launch_bounds__(256) void prep_kernel(
    const float* __restrict__ x0, const float* __restrict__ x1, const float* __restrict__ x2,
    const float* __restrict__ w0, const float* __restrict__ w1, const float* __restrict__ w2,
    unsigned short* __restrict__ Qbf, unsigned short* __restrict__ Kbf,
    unsigned short* __restrict__ Vt)
{
    __shared__ float Wf[64 * 64];
    __shared__ float xs[128 * 68];

    int m    = blockIdx.x >> 8;
    int tile = blockIdx.x & 255;
    int row0 = tile * 128;
    int b    = row0 >> 11;
    int n0   = row0 & 2047;
    const float* x = (m == 0) ? x0 : (m == 1) ? x1 : x2;
    const float* W = (m == 0) ? w0 : (m == 1) ? w1 : w2;
    int tid = threadIdx.x;

    #pragma unroll
    for (int v = 0; v < 4; ++v) {
        int i4 = v * 256 + tid;
        *(f32x4*)&Wf[i4 * 4] = *(const f32x4*)&W[i4 * 4];
    }
    #pragma unroll
    for (int v = 0; v < 8; ++v) {
        int i4 = v * 256 + tid;
        int r = i4 >> 4, c = (i4 & 15) * 4;
        *(f32x4*)&xs[r * 68 + c] = *(const f32x4*)&x[(size_t)row0 * 64 + i4 * 4];
    }
    __syncthreads();

    int lane = tid & 63, wave = tid >> 6, lq = lane & 31, h = lane >> 5;

    bf16x8 wq[2][4], wk[2][4];
    #pragma unroll
    for (int mf = 0; mf < 2; ++mf)
        #pragma unroll
        for (int kc = 0; kc < 4; ++kc) {
            int e  = mf * 32 + lq;
            int d0 = kc * 16 + h * 8;
            unsigned uq[4], uk[4];
            #pragma unroll
            for (int t = 0; t < 4; ++t) {
                int d = d0 + 2 * t;
                uq[t] = pk_rne(Wf[d * 64 + e] * QSCALE, Wf[(d + 1) * 64 + e] * QSCALE);
                uk[t] = pk_rne(Wf[e * 64 + d], Wf[e * 64 + d + 1]);
            }
            uint4 ua; ua.x = uq[0]; ua.y = uq[1]; ua.z = uq[2]; ua.w = uq[3];
            uint4 ub; ub.x = uk[0]; ub.y = uk[1]; ub.z = uk[2]; ub.w = uk[3];
            wq[mf][kc] = __builtin_bit_cast(bf16x8, ua);
            wk[mf][kc] = __builtin_bit_cast(bf16x8, ub);
        }

    bf16x8 xb[4];
    #pragma unroll
    for (int kc = 0; kc < 4; ++kc) {
        const float* xr = &xs[(wave * 32 + lq) * 68 + kc * 16 + h * 8];
        unsigned u[4];
        #pragma unroll
        for (int t = 0; t < 4; ++t) u[t] = pk_rne(xr[2 * t], xr[2 * t + 1]);
        uint4 ua; ua.x = u[0]; ua.y = u[1]; ua.z = u[2]; ua.w = u[3];
        xb[kc] = __builtin_bit_cast(bf16x8, ua);
    }

    f32x16 Qt[2], Kt[2];
    #pragma unroll
    for (int r = 0; r < 16; ++r) { Qt[0][r] = 0.f; Qt[1][r] = 0.f; Kt[0][r] = 0.f; Kt[1][r] = 0.f; }
    #pragma unroll
    for (int kc = 0; kc < 4; ++kc) {
        #pragma unroll
        for (int mf = 0; mf < 2; ++mf) {
            Qt[mf] = __builtin_amdgcn_mfma_f32_32x32x16_bf16(wq[mf][kc], xb[kc], Qt[mf], 0, 0, 0);
            Kt[mf] = __builtin_amdgcn_mfma_f32_32x32x16_bf16(wk[mf][kc], xb[kc], Kt[mf], 0, 0, 0);
        }
    }

    // ---- tiled stores -------------------------------------------------------
    size_t mbBase = ((size_t)m * B_DIM + b) * MBPLANE;
    int nn  = n0 + wave * 32 + lq;        // q/key index within (m,b)
    int g   = nn >> 6;                    // 64-row group
    int qi  = (nn >> 5) & 1;
    int ktp = nn >> 6, keyp = nn & 63;
    unsigned short* qb = Qbf + mbBase + (size_t)(g * 2 + qi) * 2048 + lq * 8;   // + c*256
    unsigned short* kb = Kbf + mbBase + (size_t)ktp * 4096 + keyp * 8;          // + c*512

    #pragma unroll
    for (int s = 0; s < 4; ++s) {
        int c = 4 * h + s;                // elem-chunk index (d-chunk)
        unsigned q00 = pk_rne(Qt[0][4 * s], Qt[0][4 * s + 1]);
        unsigned q01 = pk_rne(Qt[0][4 * s + 2], Qt[0][4 * s + 3]);
        unsigned q10 = pk_rne(Qt[1][4 * s], Qt[1][4 * s + 1]);
        unsigned q11 = pk_rne(Qt[1][4 * s + 2], Qt[1][4 * s + 3]);
        u32x2 a = half_swap(q00, q10);
        u32x2 cc = half_swap(q01, q11);
        uint4 w; w.x = a.x; w.y = cc.x; w.z = a.y; w.w = cc.y;
        *(uint4*)&qb[c * 256] = w;

        unsigned k00 = pk_rne(Kt[0][4 * s], Kt[0][4 * s + 1]);
        unsigned k01 = pk_rne(Kt[0][4 * s + 2], Kt[0][4 * s + 3]);
        unsigned k10 = pk_rne(Kt[1][4 * s], Kt[1][4 * s + 1]);
        unsigned k11 = pk_rne(Kt[1][4 * s + 2], Kt[1][4 * s + 3]);
        u32x2 a2 = half_swap(k00, k10);
        u32x2 c2 = half_swap(k01, k11);
        uint4 w2; w2.x = a2.x; w2.y = c2.x; w2.z = a2.y; w2.w = c2.y;
        *(uint4*)&kb[c * 512] = w2;
    }

    // V slabs: thread owns d = tid&63, key-range ng*32..+32
    int d  = tid & 63;
    int ng = tid >> 6;
    #pragma unroll
    for (int s = 0; s < 4; ++s) {
        int keystart = n0 + ng * 32 + 8 * s;
        int ktv = keystart >> 6;
        int cv  = (keystart & 63) >> 3;
        uint4 w;
        int rb = ng * 32 + 8 * s;
        w.x = pk_rne(xs[(rb + 0) * 68 + d], xs[(rb + 1) * 68 + d]);
        w.y = pk_rne(xs[(rb + 2) * 68 + d], xs[(rb + 3) * 68 + d]);
        w.z = pk_rne(xs[(rb + 4) * 68 + d], xs[(rb + 5) * 68 + d]);
        w.w = pk_rne(xs[(rb + 6) * 68 + d], xs[(rb + 7) * 68 + d]);
        *(uint4*)&Vt[mbBase + (size_t)(ktv * 8 + cv) * 512 + d * 8] = w;
    }
}

// ---------------------------------------------------------------------------
// attention: DOUBLE-buffered 64-key tiles (32 KB LDS). Loop iterates over
// TILES with ONE unconditional __syncthreads per iteration (no barrier in
// control flow, no duplicated MFMA blocks — R4's conditional-barrier
// restructure triggered allocator spills at the tight (256,5) budget).
// launch_bounds(256,4): budget 128 regs, natural usage ~100 (arch+acc,
// unified file) -> 4-5 waves/EU at runtime; LDS allows 5 blocks/CU.
// Per-iteration order (kt = 1..31), st carries scores across iterations:
//   exp(2kt-1); PV(2kt-1);            <- last reads of tile kt-1 buffers
//   BARRIER;  stage(kt+1);            <- publish tile kt, overwrite (kt+1)&1
//   QK(2kt); exp(2kt); QK(2kt+1); PV(2kt);
// ---------------------------------------------------------------------------
__global__ __launch_bounds__(256, 4) void attn_kernel(
    const unsigned short* __restrict__ Qbf,
    const unsigned short* __restrict__ Kbf,
    const unsigned short* __restrict__ Vt,
    unsigned short* __restrict__ part)
{
    __shared__ unsigned short Ks[2][4096];   // 8 slabs x [key 0..63][8elem]
    __shared__ unsigned short Vs[2][4096];   // 8 slabs x [d 0..63][8 keys]

    int blk = blockIdx.x;                    // 1536 = 6 pairs * 16 b * 16 qt
    int qt  = blk & 15;
    int b   = (blk >> 4) & 15;
    int p   = blk >> 8;
    int i   = p >> 1, jj = p & 1;
    int j   = i + 1 + jj; if (j >= 3) j -= 3;

    int tid = threadIdx.x, wave = tid >> 6, lane = tid & 63;
    int lq = lane & 31, h = lane >> 5;

    const unsigned short* KgT = Kbf + ((size_t)j * B_DIM + b) * MBPLANE;
    const unsigned short* VgT = Vt  + ((size_t)j * B_DIM + b) * MBPLANE;
    const unsigned short* QgT = Qbf + ((size_t)i * B_DIM + b) * MBPLANE;

    // wave stages slabs {2w, 2w+1} of K and V; global side contiguous 1KB
    int c0 = wave * 2;
    auto stage = [&](int buf, int kt) {
        const unsigned short* gk = KgT + ((size_t)(kt * 8 + c0) * 64 + lane) * 8;
        const unsigned short* gv = VgT + ((size_t)(kt * 8 + c0) * 64 + lane) * 8;
        g2lds16(gk,       &Ks[buf][c0 * 512]);
        g2lds16(gk + 512, &Ks[buf][c0 * 512 + 512]);
        g2lds16(gv,       &Vs[buf][c0 * 512]);
        g2lds16(gv + 512, &Vs[buf][c0 * 512 + 512]);
    };

    // prologue: stage tiles 0 and 1
    stage(0, 0);
    stage(1, 1);

    // Q B-frags (wave owns 32 queries: n = qt*128 + wave*32)
    int gq  = qt * 2 + (wave >> 1);
    int qih = wave & 1;
    bf16x8 qf[4];
    #pragma unroll
    for (int kc = 0; kc < 4; ++kc)
        qf[kc] = __builtin_bit_cast(bf16x8, *(const uint4*)&QgT[
            (size_t)(gq * 2 + qih) * 2048 + (kc * 2 + h) * 256 + lq * 8]);

    f32x16 O[2];                             // [df]
    #pragma unroll
    for (int r = 0; r < 16; ++r) { O[0][r] = 0.f; O[1][r] = 0.f; }
    f32x2 ls2; ls2.x = 0.f; ls2.y = 0.f;

    // QK of one 32-key half-stage: scores from K buffer, kf selects half
    auto QK = [&](const unsigned short* Kb, int kf) -> f32x16 {
        bf16x8 kfr[4];
        #pragma unroll
        for (int kc = 0; kc < 4; ++kc)
            kfr[kc] = __builtin_bit_cast(bf16x8,
                *(const uint4*)&Kb[(2 * kc + h) * 512 + (kf * 32 + lq) * 8]);
        f32x16 acc;
        #pragma unroll
        for (int r = 0; r < 16; ++r) acc[r] = 0.f;
        #pragma unroll
        for (int kc = 0; kc < 4; ++kc)
            acc = __builtin_amdgcn_mfma_f32_32x32x16_bf16(kfr[kc], qf[kc], acc, 0, 0, 0);
        return acc;
    };

    // exp2 + lsum + pack scores into two bf16x8 P-fragments
    auto EXPP = [&](const f32x16& stv, bf16x8 pf[2]) {
        unsigned pkk[4][2];
        #pragma unroll
        for (int s = 0; s < 4; ++s) {
            float e0 = __builtin_amdgcn_exp2f(stv[4 * s + 0]);
            float e1 = __builtin_amdgcn_exp2f(stv[4 * s + 1]);
            float e2 = __builtin_amdgcn_exp2f(stv[4 * s + 2]);
            float e3 = __builtin_amdgcn_exp2f(stv[4 * s + 3]);
            f32x2 p01; p01.x = e0; p01.y = e1;
            f32x2 p23; p23.x = e2; p23.y = e3;
            ls2 += p01;                      // v_pk_add_f32
            ls2 += p23;
            pkk[s][0] = __builtin_amdgcn_perm(
                __builtin_bit_cast(unsigned, e1), __builtin_bit_cast(unsigned, e0), 0x07060302u);
            pkk[s][1] = __builtin_amdgcn_perm(
                __builtin_bit_cast(unsigned, e3), __builtin_bit_cast(unsigned, e2), 0x07060302u);
        }
        #pragma unroll
        for (int c = 0; c < 2; ++c) {
            u32x2 rr0 = half_swap(pkk[2 * c][0], pkk[2 * c + 1][0]);
            u32x2 rr1 = half_swap(pkk[2 * c][1], pkk[2 * c + 1][1]);
            uint4 t; t.x = rr0.x; t.y = rr1.x; t.z = rr0.y; t.w = rr1.y;
            pf[c] = __builtin_bit_cast(bf16x8, t);
        }
    };

    // PV of one half-stage: accumulate into O from V buffer, kfp selects half
    auto PV = [&](const bf16x8 pf[2], const unsigned short* Vb, int kfp) {
        #pragma unroll
        for (int c = 0; c < 2; ++c) {
            int kcpv = 2 * kfp + c;
            #pragma unroll
            for (int df = 0; df < 2; ++df) {
                bf16x8 vfr = __builtin_bit_cast(bf16x8,
                    *(const uint4*)&Vb[(2 * kcpv + h) * 512 + (df * 32 + lq) * 8]);
                O[df] = __builtin_amdgcn_mfma_f32_32x32x16_bf16(vfr, pf[c], O[df], 0, 0, 0);
            }
        }
    };

    __syncthreads();    // publishes tiles 0,1

    // prologue compute: stage 0 (tile 0 kf0) and start of stage 1
    f32x16 st = QK(Ks[0], 0);
    {
        bf16x8 pfA[2];
        EXPP(st, pfA);                       // stage 0
        st = QK(Ks[0], 1);                   // stage 1
        PV(pfA, Vs[0], 0);                   // stage 0
    }

    for (int kt = 1; kt < 32; ++kt) {
        {
            bf16x8 pfB[2];
            EXPP(st, pfB);                   // stage 2kt-1 (tile kt-1, kf1)
            PV(pfB, Vs[(kt - 1) & 1], 1);    // last read of tile kt-1 V
        }
        __syncthreads();                     // publish tile kt; tile kt-1 bufs free
        if (kt < 31) stage((kt + 1) & 1, kt + 1);
        st = QK(Ks[kt & 1], 0);              // stage 2kt
        {
            bf16x8 pfC[2];
            EXPP(st, pfC);                   // stage 2kt
            st = QK(Ks[kt & 1], 1);          // stage 2kt+1
            PV(pfC, Vs[kt & 1], 0);          // stage 2kt
        }
    }

    // drain: stage 63 (tile 31, kf1, buf 1)
    {
        bf16x8 pfD[2];
        EXPP(st, pfD);
        PV(pfD, Vs[1], 1);
    }

    // epilogue: normalize, half-swap to row layout, store bf16 partial rows
    {
        float l = ls2.x + ls2.y;
        l += __shfl_xor(l, 32);
        float inv = 1.0f / l;
        #pragma unroll
        for (int r = 0; r < 16; ++r) { O[0][r] *= inv; O[1][r] *= inv; }

        unsigned short* dst = part + ((size_t)jj * 3 + i) * PLANE
            + (size_t)(b * N_DIM + qt * 128 + wave * 32 + lq) * 64 + h * 32;
        #pragma unroll
        for (int s = 0; s < 4; ++s) {
            unsigned t00 = pk_rne(O[0][4 * s], O[0][4 * s + 1]);
            unsigned t01 = pk_rne(O[0][4 * s + 2], O[0][4 * s + 3]);
            unsigned t10 = pk_rne(O[1][4 * s], O[1][4 * s + 1]);
            unsigned t11 = pk_rne(O[1][4 * s + 2], O[1][4 * s + 3]);
            u32x2 a = half_swap(t00, t10);
            u32x2 c = half_swap(t01, t11);
            uint4 w; w.x = a.x; w.y = c.x; w.z = a.y; w.w = c.y;
            *(uint4*)&dst[s * 8] = w;
        }
    }
}

// ---------------------------------------------------------------------------
// reduce: out = (1/3) * sum of 6 bf16 partial planes
// ---------------------------------------------------------------------------
__global__ __launch_bounds__(256) void reduce_kernel(
    const unsigned short* __restrict__ part, float* __restrict__ out)
{
    size_t e = ((size_t)blockIdx.x * 256 + threadIdx.x) * 4;
    float a0 = 0.f, a1 = 0.f, a2 = 0.f, a3 = 0.f;
    #pragma unroll
    for (int q = 0; q < 6; ++q) {
        const unsigned short* pp = part + (size_t)q * PLANE + e;
        unsigned u0 = *(const unsigned*)&pp[0];
        unsigned u1 = *(const unsigned*)&pp[2];
        a0 += __builtin_bit_cast(float, u0 << 16);
        a1 += __builtin_bit_cast(float, u0 & 0xffff0000u);
        a2 += __builtin_bit_cast(float, u1 << 16);
        a3 += __builtin_bit_cast(float, u1 & 0xffff0000u);
    }
    f32x4 v;
    v.x = a0 * (1.0f / 3.0f); v.y = a1 * (1.0f / 3.0f);
    v.z = a2 * (1.0f / 3.0f); v.w = a3 * (1.0f / 3.0f);
    *(f32x4*)&out[e] = v;
}

extern "C" void kernel_launch(void* const* d_in, const int* in_sizes, int n_in,
                              void* d_out, int out_size, void* d_ws, size_t ws_size,
                              hipStream_t stream)
{
    const float* x0 = (const float*)d_in[0];
    const float* x1 = (const float*)d_in[1];
    const float* x2 = (const float*)d_in[2];
    const float* w0 = (const float*)d_in[3];
    const float* w1 = (const float*)d_in[4];
    const float* w2 = (const float*)d_in[5];
    float* out = (float*)d_out;

    size_t nElem = (size_t)3 * BN * 64;
    unsigned short* Qbf = (unsigned short*)d_ws;
    unsigned short* Kbf = Qbf + nElem;
    unsigned short* Vt  = Kbf + nElem;
    unsigned short* part = Vt + nElem;      // 6 planes * BN*64 bf16

    hipLaunchKernelGGL(prep_kernel, dim3(3 * (BN / 128)), dim3(256), 0, stream,
                       x0, x1, x2, w0, w1, w2, Qbf, Kbf, Vt);
    hipLaunchKernelGGL(attn_kernel, dim3(6 * B_DIM * (N_DIM / 128)), dim3(256), 0, stream,
                       Qbf, Kbf, Vt, part);
    hipLaunchKernelGGL(reduce_kernel, dim3((BN * 64 / 4) / 256), dim3(256), 0, stream,
                       part, out);
}

// Round 6
// 207.649 us; speedup vs baseline: 5.1851x; 1.0043x over previous
//
#include <hip/hip_runtime.h>
#include <cstdint>
#include <cstddef>

#define B_DIM 16
#define N_DIM 2048
#define BN (B_DIM * N_DIM)          // 32768 rows per modality
#define QSCALE 0.18033688f          // 0.125 * log2(e): P = exp2(S')
#define PLANE ((size_t)BN * 64)     // elems per (jj,i) partial plane
#define MBPLANE ((size_t)N_DIM * 64) // elems per (modality,batch) tensor block

typedef __attribute__((ext_vector_type(4))) float f32x4;
typedef __attribute__((ext_vector_type(2))) float f32x2;
typedef __attribute__((ext_vector_type(16))) float f32x16;
typedef __attribute__((ext_vector_type(8))) __bf16 bf16x8;
typedef __attribute__((ext_vector_type(2))) unsigned int u32x2;

__device__ __forceinline__ unsigned short f2bf_rne(float f) {
    union { float f; unsigned int u; } v; v.f = f;
    unsigned int u = v.u;
    return (unsigned short)((u + 0x7fffu + ((u >> 16) & 1u)) >> 16);
}
__device__ __forceinline__ unsigned pk_rne(float a, float b) {
    return (unsigned)f2bf_rne(a) | ((unsigned)f2bf_rne(b) << 16);
}
// half_swap(a,b): res.x = {a.lo32, b.lo32}, res.y = {a.hi32, b.hi32}
__device__ __forceinline__ u32x2 half_swap(unsigned a, unsigned b) {
#if __has_builtin(__builtin_amdgcn_permlane32_swap)
    return __builtin_amdgcn_permlane32_swap(a, b, false, false);
#else
    unsigned pa = (unsigned)__shfl_xor((int)a, 32);
    unsigned pb = (unsigned)__shfl_xor((int)b, 32);
    bool hi = (threadIdx.x & 32) != 0;
    u32x2 r;
    r.x = hi ? pb : a;
    r.y = hi ? b : pa;
    return r;
#endif
}

// async global->LDS, 16B per lane; LDS dest = wave-uniform base + lane*16
__device__ __forceinline__ void g2lds16(const unsigned short* g, unsigned short* ldsbase) {
#if __has_builtin(__builtin_amdgcn_global_load_lds)
    __builtin_amdgcn_global_load_lds(
        (const __attribute__((address_space(1))) unsigned int*)g,
        (__attribute__((address_space(3))) unsigned int*)ldsbase,
        16, 0, 0);
#else
    int ln = threadIdx.x & 63;
    *(uint4*)(ldsbase + ln * 8) = *(const uint4*)g;
#endif
}

// ---------------------------------------------------------------------------
// prep (MFMA): Q = (x@W)*QSCALE, K = x@W^T, V = x^T — all emitted in TILED
// slab layouts (R0-verified):
//   Q: [m][b][g=q/64][qi=(q>>5)&1][chunk 0..7][lq=q&31][8elem]
//   K: [m][b][kt=key/64][chunk 0..7][key&63][8elem]      (chunk = d/8)
//   V: [m][b][kt][chunk=keygrp 0..7][d 0..63][8 keys]    (x^T slabs)
// ---------------------------------------------------------------------------
__global__ __launch_bounds__(256) void prep_kernel(
    const float* __restrict__ x0, const float* __restrict__ x1, const float* __restrict__ x2,
    const float* __restrict__ w0, const float* __restrict__ w1, const float* __restrict__ w2,
    unsigned short* __restrict__ Qbf, unsigned short* __restrict__ Kbf,
    unsigned short* __restrict__ Vt)
{
    __shared__ float Wf[64 * 64];
    __shared__ float xs[128 * 68];

    int m    = blockIdx.x >> 8;
    int tile = blockIdx.x & 255;
    int row0 = tile * 128;
    int b    = row0 >> 11;
    int n0   = row0 & 2047;
    const float* x = (m == 0) ? x0 : (m == 1) ? x1 : x2;
    const float* W = (m == 0) ? w0 : (m == 1) ? w1 : w2;
    int tid = threadIdx.x;

    #pragma unroll
    for (int v = 0; v < 4; ++v) {
        int i4 = v * 256 + tid;
        *(f32x4*)&Wf[i4 * 4] = *(const f32x4*)&W[i4 * 4];
    }
    #pragma unroll
    for (int v = 0; v < 8; ++v) {
        int i4 = v * 256 + tid;
        int r = i4 >> 4, c = (i4 & 15) * 4;
        *(f32x4*)&xs[r * 68 + c] = *(const f32x4*)&x[(size_t)row0 * 64 + i4 * 4];
    }
    __syncthreads();

    int lane = tid & 63, wave = tid >> 6, lq = lane & 31, h = lane >> 5;

    bf16x8 wq[2][4], wk[2][4];
    #pragma unroll
    for (int mf = 0; mf < 2; ++mf)
        #pragma unroll
        for (int kc = 0; kc < 4; ++kc) {
            int e  = mf * 32 + lq;
            int d0 = kc * 16 + h * 8;
            unsigned uq[4], uk[4];
            #pragma unroll
            for (int t = 0; t < 4; ++t) {
                int d = d0 + 2 * t;
                uq[t] = pk_rne(Wf[d * 64 + e] * QSCALE, Wf[(d + 1) * 64 + e] * QSCALE);
                uk[t] = pk_rne(Wf[e * 64 + d], Wf[e * 64 + d + 1]);
            }
            uint4 ua; ua.x = uq[0]; ua.y = uq[1]; ua.z = uq[2]; ua.w = uq[3];
            uint4 ub; ub.x = uk[0]; ub.y = uk[1]; ub.z = uk[2]; ub.w = uk[3];
            wq[mf][kc] = __builtin_bit_cast(bf16x8, ua);
            wk[mf][kc] = __builtin_bit_cast(bf16x8, ub);
        }

    bf16x8 xb[4];
    #pragma unroll
    for (int kc = 0; kc < 4; ++kc) {
        const float* xr = &xs[(wave * 32 + lq) * 68 + kc * 16 + h * 8];
        unsigned u[4];
        #pragma unroll
        for (int t = 0; t < 4; ++t) u[t] = pk_rne(xr[2 * t], xr[2 * t + 1]);
        uint4 ua; ua.x = u[0]; ua.y = u[1]; ua.z = u[2]; ua.w = u[3];
        xb[kc] = __builtin_bit_cast(bf16x8, ua);
    }

    f32x16 Qt[2], Kt[2];
    #pragma unroll
    for (int r = 0; r < 16; ++r) { Qt[0][r] = 0.f; Qt[1][r] = 0.f; Kt[0][r] = 0.f; Kt[1][r] = 0.f; }
    #pragma unroll
    for (int kc = 0; kc < 4; ++kc) {
        #pragma unroll
        for (int mf = 0; mf < 2; ++mf) {
            Qt[mf] = __builtin_amdgcn_mfma_f32_32x32x16_bf16(wq[mf][kc], xb[kc], Qt[mf], 0, 0, 0);
            Kt[mf] = __builtin_amdgcn_mfma_f32_32x32x16_bf16(wk[mf][kc], xb[kc], Kt[mf], 0, 0, 0);
        }
    }

    // ---- tiled stores -------------------------------------------------------
    size_t mbBase = ((size_t)m * B_DIM + b) * MBPLANE;
    int nn  = n0 + wave * 32 + lq;        // q/key index within (m,b)
    int g   = nn >> 6;                    // 64-row group
    int qi  = (nn >> 5) & 1;
    int ktp = nn >> 6, keyp = nn & 63;
    unsigned short* qb = Qbf + mbBase + (size_t)(g * 2 + qi) * 2048 + lq * 8;   // + c*256
    unsigned short* kb = Kbf + mbBase + (size_t)ktp * 4096 + keyp * 8;          // + c*512

    #pragma unroll
    for (int s = 0; s < 4; ++s) {
        int c = 4 * h + s;                // elem-chunk index (d-chunk)
        unsigned q00 = pk_rne(Qt[0][4 * s], Qt[0][4 * s + 1]);
        unsigned q01 = pk_rne(Qt[0][4 * s + 2], Qt[0][4 * s + 3]);
        unsigned q10 = pk_rne(Qt[1][4 * s], Qt[1][4 * s + 1]);
        unsigned q11 = pk_rne(Qt[1][4 * s + 2], Qt[1][4 * s + 3]);
        u32x2 a = half_swap(q00, q10);
        u32x2 cc = half_swap(q01, q11);
        uint4 w; w.x = a.x; w.y = cc.x; w.z = a.y; w.w = cc.y;
        *(uint4*)&qb[c * 256] = w;

        unsigned k00 = pk_rne(Kt[0][4 * s], Kt[0][4 * s + 1]);
        unsigned k01 = pk_rne(Kt[0][4 * s + 2], Kt[0][4 * s + 3]);
        unsigned k10 = pk_rne(Kt[1][4 * s], Kt[1][4 * s + 1]);
        unsigned k11 = pk_rne(Kt[1][4 * s + 2], Kt[1][4 * s + 3]);
        u32x2 a2 = half_swap(k00, k10);
        u32x2 c2 = half_swap(k01, k11);
        uint4 w2; w2.x = a2.x; w2.y = c2.x; w2.z = a2.y; w2.w = c2.y;
        *(uint4*)&kb[c * 512] = w2;
    }

    // V slabs: thread owns d = tid&63, key-range ng*32..+32
    int d  = tid & 63;
    int ng = tid >> 6;
    #pragma unroll
    for (int s = 0; s < 4; ++s) {
        int keystart = n0 + ng * 32 + 8 * s;
        int ktv = keystart >> 6;
        int cv  = (keystart & 63) >> 3;
        uint4 w;
        int rb = ng * 32 + 8 * s;
        w.x = pk_rne(xs[(rb + 0) * 68 + d], xs[(rb + 1) * 68 + d]);
        w.y = pk_rne(xs[(rb + 2) * 68 + d], xs[(rb + 3) * 68 + d]);
        w.z = pk_rne(xs[(rb + 4) * 68 + d], xs[(rb + 5) * 68 + d]);
        w.w = pk_rne(xs[(rb + 6) * 68 + d], xs[(rb + 7) * 68 + d]);
        *(uint4*)&Vt[mbBase + (size_t)(ktv * 8 + cv) * 512 + d * 8] = w;
    }
}

// ---------------------------------------------------------------------------
// attention R6: 64 queries/wave (best LDS-read/MFMA ratio: 8 ds_read_b128
// per 16 MFMAs), 256q blocks, grid 768. Double-buffered 64-key tiles
// (32 KB LDS), PV-before-barrier order (R5-proven legality). Instruction
// cuts vs R0: ZERO-C accumulator init (no per-stage v_mov zeroing),
// interleaved qi MFMA chains, s_setprio around MFMA clusters, pk_add lsum.
// ---------------------------------------------------------------------------
__global__ __launch_bounds__(256, 3) void attn_kernel(
    const unsigned short* __restrict__ Qbf,
    const unsigned short* __restrict__ Kbf,
    const unsigned short* __restrict__ Vt,
    unsigned short* __restrict__ part)
{
    __shared__ unsigned short Ks[2][4096];   // 8 slabs x [key 0..63][8elem]
    __shared__ unsigned short Vs[2][4096];   // 8 slabs x [d 0..63][8 keys]

    int blk = blockIdx.x;                    // 768 = 6 pairs * 16 b * 8 qt
    int qt  = blk & 7;
    int b   = (blk >> 3) & 15;
    int p   = blk >> 7;
    int i   = p >> 1, jj = p & 1;
    int j   = i + 1 + jj; if (j >= 3) j -= 3;

    int tid = threadIdx.x, wave = tid >> 6, lane = tid & 63;
    int lq = lane & 31, h = lane >> 5;

    const unsigned short* KgT = Kbf + ((size_t)j * B_DIM + b) * MBPLANE;
    const unsigned short* VgT = Vt  + ((size_t)j * B_DIM + b) * MBPLANE;
    const unsigned short* QgT = Qbf + ((size_t)i * B_DIM + b) * MBPLANE;

    // wave stages slabs {2w, 2w+1} of K and V; global side contiguous 1KB
    int c0 = wave * 2;
    auto stage = [&](int buf, int kt) {
        const unsigned short* gk = KgT + ((size_t)(kt * 8 + c0) * 64 + lane) * 8;
        const unsigned short* gv = VgT + ((size_t)(kt * 8 + c0) * 64 + lane) * 8;
        g2lds16(gk,       &Ks[buf][c0 * 512]);
        g2lds16(gk + 512, &Ks[buf][c0 * 512 + 512]);
        g2lds16(gv,       &Vs[buf][c0 * 512]);
        g2lds16(gv + 512, &Vs[buf][c0 * 512 + 512]);
    };

    // prologue: stage tiles 0 and 1
    stage(0, 0);
    stage(1, 1);

    // Q B-frags: wave owns 64 queries (q = qt*256 + wave*64 + qi*32 + lq)
    int g0 = qt * 4 + wave;
    bf16x8 qf[2][4];
    #pragma unroll
    for (int qi = 0; qi < 2; ++qi)
        #pragma unroll
        for (int kc = 0; kc < 4; ++kc)
            qf[qi][kc] = __builtin_bit_cast(bf16x8, *(const uint4*)&QgT[
                (size_t)(g0 * 2 + qi) * 2048 + (kc * 2 + h) * 256 + lq * 8]);

    // loop-invariant zero accumulator (C-operand; avoids per-stage v_movs)
    f32x16 ZERO;
    #pragma unroll
    for (int r = 0; r < 16; ++r) ZERO[r] = 0.f;

    f32x16 O[2][2];                          // [df][qi]
    #pragma unroll
    for (int r = 0; r < 16; ++r) { O[0][0][r] = 0.f; O[0][1][r] = 0.f; O[1][0][r] = 0.f; O[1][1][r] = 0.f; }
    f32x2 ls2[2]; ls2[0] = (f32x2)(0.f); ls2[1] = (f32x2)(0.f);

    // QK of one 32-key half-stage for both qi; interleaved independent chains
    auto QK = [&](const unsigned short* Kb, int kf, f32x16 stv[2]) {
        bf16x8 kfr[4];
        #pragma unroll
        for (int kc = 0; kc < 4; ++kc)
            kfr[kc] = __builtin_bit_cast(bf16x8,
                *(const uint4*)&Kb[(2 * kc + h) * 512 + (kf * 32 + lq) * 8]);
        __builtin_amdgcn_s_setprio(1);
        stv[0] = __builtin_amdgcn_mfma_f32_32x32x16_bf16(kfr[0], qf[0][0], ZERO, 0, 0, 0);
        stv[1] = __builtin_amdgcn_mfma_f32_32x32x16_bf16(kfr[0], qf[1][0], ZERO, 0, 0, 0);
        #pragma unroll
        for (int kc = 1; kc < 4; ++kc) {
            stv[0] = __builtin_amdgcn_mfma_f32_32x32x16_bf16(kfr[kc], qf[0][kc], stv[0], 0, 0, 0);
            stv[1] = __builtin_amdgcn_mfma_f32_32x32x16_bf16(kfr[kc], qf[1][kc], stv[1], 0, 0, 0);
        }
        __builtin_amdgcn_s_setprio(0);
    };

    // exp2 + lsum + pack scores into P-fragments for both qi
    auto EXPP = [&](const f32x16 stv[2], bf16x8 pf[2][2]) {
        #pragma unroll
        for (int qi = 0; qi < 2; ++qi) {
            unsigned pkk[4][2];
            #pragma unroll
            for (int s = 0; s < 4; ++s) {
                float e0 = __builtin_amdgcn_exp2f(stv[qi][4 * s + 0]);
                float e1 = __builtin_amdgcn_exp2f(stv[qi][4 * s + 1]);
                float e2 = __builtin_amdgcn_exp2f(stv[qi][4 * s + 2]);
                float e3 = __builtin_amdgcn_exp2f(stv[qi][4 * s + 3]);
                f32x2 p01; p01.x = e0; p01.y = e1;
                f32x2 p23; p23.x = e2; p23.y = e3;
                ls2[qi] += p01;              // v_pk_add_f32
                ls2[qi] += p23;
                pkk[s][0] = __builtin_amdgcn_perm(
                    __builtin_bit_cast(unsigned, e1), __builtin_bit_cast(unsigned, e0), 0x07060302u);
                pkk[s][1] = __builtin_amdgcn_perm(
                    __builtin_bit_cast(unsigned, e3), __builtin_bit_cast(unsigned, e2), 0x07060302u);
            }
            #pragma unroll
            for (int c = 0; c < 2; ++c) {
                u32x2 rr0 = half_swap(pkk[2 * c][0], pkk[2 * c + 1][0]);
                u32x2 rr1 = half_swap(pkk[2 * c][1], pkk[2 * c + 1][1]);
                uint4 t; t.x = rr0.x; t.y = rr1.x; t.z = rr0.y; t.w = rr1.y;
                pf[qi][c] = __builtin_bit_cast(bf16x8, t);
            }
        }
    };

    // PV of one half-stage: 4 shared vfr reads feed both qi accumulators
    auto PV = [&](const bf16x8 pf[2][2], const unsigned short* Vb, int kfp) {
        #pragma unroll
        for (int c = 0; c < 2; ++c) {
            int kcpv = 2 * kfp + c;
            bf16x8 vfr0 = __builtin_bit_cast(bf16x8,
                *(const uint4*)&Vb[(2 * kcpv + h) * 512 + lq * 8]);
            bf16x8 vfr1 = __builtin_bit_cast(bf16x8,
                *(const uint4*)&Vb[(2 * kcpv + h) * 512 + (32 + lq) * 8]);
            __builtin_amdgcn_s_setprio(1);
            O[0][0] = __builtin_amdgcn_mfma_f32_32x32x16_bf16(vfr0, pf[0][c], O[0][0], 0, 0, 0);
            O[0][1] = __builtin_amdgcn_mfma_f32_32x32x16_bf16(vfr0, pf[1][c], O[0][1], 0, 0, 0);
            O[1][0] = __builtin_amdgcn_mfma_f32_32x32x16_bf16(vfr1, pf[0][c], O[1][0], 0, 0, 0);
            O[1][1] = __builtin_amdgcn_mfma_f32_32x32x16_bf16(vfr1, pf[1][c], O[1][1], 0, 0, 0);
            __builtin_amdgcn_s_setprio(0);
        }
    };

    __syncthreads();    // publishes tiles 0,1

    // prologue compute: stage 0 (tile 0 kf0) and start of stage 1
    f32x16 st[2];
    QK(Ks[0], 0, st);
    {
        bf16x8 pfA[2][2];
        EXPP(st, pfA);                       // stage 0
        QK(Ks[0], 1, st);                    // stage 1
        PV(pfA, Vs[0], 0);                   // stage 0
    }

    for (int kt = 1; kt < 32; ++kt) {
        {
            bf16x8 pfB[2][2];
            EXPP(st, pfB);                   // stage 2kt-1 (tile kt-1, kf1)
            PV(pfB, Vs[(kt - 1) & 1], 1);    // last read of tile kt-1 V
        }
        __syncthreads();                     // publish tile kt; tile kt-1 bufs free
        if (kt < 31) stage((kt + 1) & 1, kt + 1);
        QK(Ks[kt & 1], 0, st);               // stage 2kt
        {
            bf16x8 pfC[2][2];
            EXPP(st, pfC);                   // stage 2kt
            QK(Ks[kt & 1], 1, st);           // stage 2kt+1
            PV(pfC, Vs[kt & 1], 0);          // stage 2kt
        }
    }

    // drain: stage 63 (tile 31, kf1, buf 1)
    {
        bf16x8 pfD[2][2];
        EXPP(st, pfD);
        PV(pfD, Vs[1], 1);
    }

    // epilogue: normalize, half-swap to row layout, store bf16 partial rows
    #pragma unroll
    for (int qi = 0; qi < 2; ++qi) {
        float l = ls2[qi].x + ls2[qi].y;
        l += __shfl_xor(l, 32);
        float inv = 1.0f / l;
        #pragma unroll
        for (int r = 0; r < 16; ++r) { O[0][qi][r] *= inv; O[1][qi][r] *= inv; }

        unsigned short* dst = part + ((size_t)jj * 3 + i) * PLANE
            + (size_t)(b * N_DIM + qt * 256 + wave * 64 + qi * 32 + lq) * 64 + h * 32;
        #pragma unroll
        for (int s = 0; s < 4; ++s) {
            unsigned t00 = pk_rne(O[0][qi][4 * s], O[0][qi][4 * s + 1]);
            unsigned t01 = pk_rne(O[0][qi][4 * s + 2], O[0][qi][4 * s + 3]);
            unsigned t10 = pk_rne(O[1][qi][4 * s], O[1][qi][4 * s + 1]);
            unsigned t11 = pk_rne(O[1][qi][4 * s + 2], O[1][qi][4 * s + 3]);
            u32x2 a = half_swap(t00, t10);
            u32x2 c = half_swap(t01, t11);
            uint4 w; w.x = a.x; w.y = c.x; w.z = a.y; w.w = c.y;
            *(uint4*)&dst[s * 8] = w;
        }
    }
}

// ---------------------------------------------------------------------------
// reduce: out = (1/3) * sum of 6 bf16 partial planes
// ---------------------------------------------------------------------------
__global__ __launch_bounds__(256) void reduce_kernel(
    const unsigned short* __restrict__ part, float* __restrict__ out)
{
    size_t e = ((size_t)blockIdx.x * 256 + threadIdx.x) * 4;
    float a0 = 0.f, a1 = 0.f, a2 = 0.f, a3 = 0.f;
    #pragma unroll
    for (int q = 0; q < 6; ++q) {
        const unsigned short* pp = part + (size_t)q * PLANE + e;
        unsigned u0 = *(const unsigned*)&pp[0];
        unsigned u1 = *(const unsigned*)&pp[2];
        a0 += __builtin_bit_cast(float, u0 << 16);
        a1 += __builtin_bit_cast(float, u0 & 0xffff0000u);
        a2 += __builtin_bit_cast(float, u1 << 16);
        a3 += __builtin_bit_cast(float, u1 & 0xffff0000u);
    }
    f32x4 v;
    v.x = a0 * (1.0f / 3.0f); v.y = a1 * (1.0f / 3.0f);
    v.z = a2 * (1.0f / 3.0f); v.w = a3 * (1.0f / 3.0f);
    *(f32x4*)&out[e] = v;
}

extern "C" void kernel_launch(void* const* d_in, const int* in_sizes, int n_in,
                              void* d_out, int out_size, void* d_ws, size_t ws_size,
                              hipStream_t stream)
{
    const float* x0 = (const float*)d_in[0];
    const float* x1 = (const float*)d_in[1];
    const float* x2 = (const float*)d_in[2];
    const float* w0 = (const float*)d_in[3];
    const float* w1 = (const float*)d_in[4];
    const float* w2 = (const float*)d_in[5];
    float* out = (float*)d_out;

    size_t nElem = (size_t)3 * BN * 64;
    unsigned short* Qbf = (unsigned short*)d_ws;
    unsigned short* Kbf = Qbf + nElem;
    unsigned short* Vt  = Kbf + nElem;
    unsigned short* part = Vt + nElem;      // 6 planes * BN*64 bf16

    hipLaunchKernelGGL(prep_kernel, dim3(3 * (BN / 128)), dim3(256), 0, stream,
                       x0, x1, x2, w0, w1, w2, Qbf, Kbf, Vt);
    hipLaunchKernelGGL(attn_kernel, dim3(6 * B_DIM * (N_DIM / 256)), dim3(256), 0, stream,
                       Qbf, Kbf, Vt, part);
    hipLaunchKernelGGL(reduce_kernel, dim3((BN * 64 / 4) / 256), dim3(256), 0, stream,
                       part, out);
}

// Round 7
// 199.095 us; speedup vs baseline: 5.4079x; 1.0430x over previous
//
#include <hip/hip_runtime.h>
#include <cstdint>
#include <cstddef>

#define B_DIM 16
#define N_DIM 2048
#define BN (B_DIM * N_DIM)          // 32768 rows per modality
#define QSCALE 0.18033688f          // 0.125 * log2(e): P = exp2(S')
#define PLANE ((size_t)BN * 64)     // elems per (jj,i) partial plane
#define MBPLANE ((size_t)N_DIM * 64) // elems per (modality,batch) tensor block
#define WFRAG_K_OFF (3 * 8 * 64 * 8) // shorts: K-frag area offset in wfrag

typedef __attribute__((ext_vector_type(4))) float f32x4;
typedef __attribute__((ext_vector_type(2))) float f32x2;
typedef __attribute__((ext_vector_type(16))) float f32x16;
typedef __attribute__((ext_vector_type(8))) __bf16 bf16x8;
typedef __attribute__((ext_vector_type(2))) unsigned int u32x2;

__device__ __forceinline__ unsigned short f2bf_rne(float f) {
    union { float f; unsigned int u; } v; v.f = f;
    unsigned int u = v.u;
    return (unsigned short)((u + 0x7fffu + ((u >> 16) & 1u)) >> 16);
}
__device__ __forceinline__ unsigned pk_rne(float a, float b) {
    return (unsigned)f2bf_rne(a) | ((unsigned)f2bf_rne(b) << 16);
}
// half_swap(a,b): res.x = {a.lo32, b.lo32}, res.y = {a.hi32, b.hi32}
__device__ __forceinline__ u32x2 half_swap(unsigned a, unsigned b) {
#if __has_builtin(__builtin_amdgcn_permlane32_swap)
    return __builtin_amdgcn_permlane32_swap(a, b, false, false);
#else
    unsigned pa = (unsigned)__shfl_xor((int)a, 32);
    unsigned pb = (unsigned)__shfl_xor((int)b, 32);
    bool hi = (threadIdx.x & 32) != 0;
    u32x2 r;
    r.x = hi ? pb : a;
    r.y = hi ? b : pa;
    return r;
#endif
}

// async global->LDS, 16B per lane; LDS dest = wave-uniform base + lane*16
__device__ __forceinline__ void g2lds16(const unsigned short* g, unsigned short* ldsbase) {
#if __has_builtin(__builtin_amdgcn_global_load_lds)
    __builtin_amdgcn_global_load_lds(
        (const __attribute__((address_space(1))) unsigned int*)g,
        (__attribute__((address_space(3))) unsigned int*)ldsbase,
        16, 0, 0);
#else
    int ln = threadIdx.x & 63;
    *(uint4*)(ldsbase + ln * 8) = *(const uint4*)g;
#endif
}

// ---------------------------------------------------------------------------
// wprep: per-lane W fragments (wq scaled, wk) computed ONCE per modality.
// Previously every one of 768 prep blocks recomputed these (64 pk_rne +
// 128 scalar LDS reads per thread). Layout (shorts):
//   WQ: [(m*8 + kc*2 + mf)*64 + lane][8]   (uint4 per frag)
//   WK: same, at +WFRAG_K_OFF
// ---------------------------------------------------------------------------
__global__ __launch_bounds__(64) void wprep_kernel(
    const float* __restrict__ w0, const float* __restrict__ w1, const float* __restrict__ w2,
    unsigned short* __restrict__ wfrag)
{
    int m = blockIdx.x;
    const float* W = (m == 0) ? w0 : (m == 1) ? w1 : w2;
    int lane = threadIdx.x;
    int lq = lane & 31, h = lane >> 5;

    #pragma unroll
    for (int mf = 0; mf < 2; ++mf)
        #pragma unroll
        for (int kc = 0; kc < 4; ++kc) {
            int e  = mf * 32 + lq;
            int d0 = kc * 16 + h * 8;
            unsigned uq[4], uk[4];
            #pragma unroll
            for (int t = 0; t < 4; ++t) {
                int d = d0 + 2 * t;
                uq[t] = pk_rne(W[d * 64 + e] * QSCALE, W[(d + 1) * 64 + e] * QSCALE);
                uk[t] = pk_rne(W[e * 64 + d], W[e * 64 + d + 1]);
            }
            unsigned short* dq = wfrag + ((size_t)((m * 8 + kc * 2 + mf) * 64 + lane)) * 8;
            uint4 a; a.x = uq[0]; a.y = uq[1]; a.z = uq[2]; a.w = uq[3];
            uint4 b; b.x = uk[0]; b.y = uk[1]; b.z = uk[2]; b.w = uk[3];
            *(uint4*)dq = a;
            *(uint4*)(dq + WFRAG_K_OFF) = b;
        }
}

// ---------------------------------------------------------------------------
// prep (MFMA): Q = (x@W)*QSCALE, K = x@W^T, V = x^T — all emitted in TILED
// slab layouts (R0-verified):
//   Q: [m][b][g=q/64][qi=(q>>5)&1][chunk 0..7][lq=q&31][8elem]
//   K: [m][b][kt=key/64][chunk 0..7][key&63][8elem]      (chunk = d/8)
//   V: [m][b][kt][chunk=keygrp 0..7][d 0..63][8 keys]    (x^T slabs)
// W fragments loaded from wprep output (16 coalesced uint4/thread).
// ---------------------------------------------------------------------------
__global__ __launch_bounds__(256) void prep_kernel(
    const float* __restrict__ x0, const float* __restrict__ x1, const float* __restrict__ x2,
    const unsigned short* __restrict__ wfrag,
    unsigned short* __restrict__ Qbf, unsigned short* __restrict__ Kbf,
    unsigned short* __restrict__ Vt)
{
    __shared__ float xs[128 * 68];

    int m    = blockIdx.x >> 8;
    int tile = blockIdx.x & 255;
    int row0 = tile * 128;
    int b    = row0 >> 11;
    int n0   = row0 & 2047;
    const float* x = (m == 0) ? x0 : (m == 1) ? x1 : x2;
    int tid = threadIdx.x;

    #pragma unroll
    for (int v = 0; v < 8; ++v) {
        int i4 = v * 256 + tid;
        int r = i4 >> 4, c = (i4 & 15) * 4;
        *(f32x4*)&xs[r * 68 + c] = *(const f32x4*)&x[(size_t)row0 * 64 + i4 * 4];
    }
    __syncthreads();

    int lane = tid & 63, wave = tid >> 6, lq = lane & 31, h = lane >> 5;

    bf16x8 wq[2][4], wk[2][4];
    #pragma unroll
    for (int mf = 0; mf < 2; ++mf)
        #pragma unroll
        for (int kc = 0; kc < 4; ++kc) {
            const unsigned short* fq = wfrag + ((size_t)((m * 8 + kc * 2 + mf) * 64 + lane)) * 8;
            wq[mf][kc] = __builtin_bit_cast(bf16x8, *(const uint4*)fq);
            wk[mf][kc] = __builtin_bit_cast(bf16x8, *(const uint4*)(fq + WFRAG_K_OFF));
        }

    bf16x8 xb[4];
    #pragma unroll
    for (int kc = 0; kc < 4; ++kc) {
        const float* xr = &xs[(wave * 32 + lq) * 68 + kc * 16 + h * 8];
        unsigned u[4];
        #pragma unroll
        for (int t = 0; t < 4; ++t) u[t] = pk_rne(xr[2 * t], xr[2 * t + 1]);
        uint4 ua; ua.x = u[0]; ua.y = u[1]; ua.z = u[2]; ua.w = u[3];
        xb[kc] = __builtin_bit_cast(bf16x8, ua);
    }

    f32x16 Qt[2], Kt[2];
    #pragma unroll
    for (int r = 0; r < 16; ++r) { Qt[0][r] = 0.f; Qt[1][r] = 0.f; Kt[0][r] = 0.f; Kt[1][r] = 0.f; }
    #pragma unroll
    for (int kc = 0; kc < 4; ++kc) {
        #pragma unroll
        for (int mf = 0; mf < 2; ++mf) {
            Qt[mf] = __builtin_amdgcn_mfma_f32_32x32x16_bf16(wq[mf][kc], xb[kc], Qt[mf], 0, 0, 0);
            Kt[mf] = __builtin_amdgcn_mfma_f32_32x32x16_bf16(wk[mf][kc], xb[kc], Kt[mf], 0, 0, 0);
        }
    }

    // ---- tiled stores -------------------------------------------------------
    size_t mbBase = ((size_t)m * B_DIM + b) * MBPLANE;
    int nn  = n0 + wave * 32 + lq;        // q/key index within (m,b)
    int g   = nn >> 6;                    // 64-row group
    int qi  = (nn >> 5) & 1;
    int ktp = nn >> 6, keyp = nn & 63;
    unsigned short* qb = Qbf + mbBase + (size_t)(g * 2 + qi) * 2048 + lq * 8;   // + c*256
    unsigned short* kb = Kbf + mbBase + (size_t)ktp * 4096 + keyp * 8;          // + c*512

    #pragma unroll
    for (int s = 0; s < 4; ++s) {
        int c = 4 * h + s;                // elem-chunk index (d-chunk)
        unsigned q00 = pk_rne(Qt[0][4 * s], Qt[0][4 * s + 1]);
        unsigned q01 = pk_rne(Qt[0][4 * s + 2], Qt[0][4 * s + 3]);
        unsigned q10 = pk_rne(Qt[1][4 * s], Qt[1][4 * s + 1]);
        unsigned q11 = pk_rne(Qt[1][4 * s + 2], Qt[1][4 * s + 3]);
        u32x2 a = half_swap(q00, q10);
        u32x2 cc = half_swap(q01, q11);
        uint4 w; w.x = a.x; w.y = cc.x; w.z = a.y; w.w = cc.y;
        *(uint4*)&qb[c * 256] = w;

        unsigned k00 = pk_rne(Kt[0][4 * s], Kt[0][4 * s + 1]);
        unsigned k01 = pk_rne(Kt[0][4 * s + 2], Kt[0][4 * s + 3]);
        unsigned k10 = pk_rne(Kt[1][4 * s], Kt[1][4 * s + 1]);
        unsigned k11 = pk_rne(Kt[1][4 * s + 2], Kt[1][4 * s + 3]);
        u32x2 a2 = half_swap(k00, k10);
        u32x2 c2 = half_swap(k01, k11);
        uint4 w2; w2.x = a2.x; w2.y = c2.x; w2.z = a2.y; w2.w = c2.y;
        *(uint4*)&kb[c * 512] = w2;
    }

    // V slabs: thread owns d = tid&63, key-range ng*32..+32
    int d  = tid & 63;
    int ng = tid >> 6;
    #pragma unroll
    for (int s = 0; s < 4; ++s) {
        int keystart = n0 + ng * 32 + 8 * s;
        int ktv = keystart >> 6;
        int cv  = (keystart & 63) >> 3;
        uint4 w;
        int rb = ng * 32 + 8 * s;
        w.x = pk_rne(xs[(rb + 0) * 68 + d], xs[(rb + 1) * 68 + d]);
        w.y = pk_rne(xs[(rb + 2) * 68 + d], xs[(rb + 3) * 68 + d]);
        w.z = pk_rne(xs[(rb + 4) * 68 + d], xs[(rb + 5) * 68 + d]);
        w.w = pk_rne(xs[(rb + 6) * 68 + d], xs[(rb + 7) * 68 + d]);
        *(uint4*)&Vt[mbBase + (size_t)(ktv * 8 + cv) * 512 + d * 8] = w;
    }
}

// ---------------------------------------------------------------------------
// attention R7: R6 structure (64q/wave, 2-buf 32 KB, PV-before-barrier)
// minus setprio (null in barrier-lockstep regime), plus XCD-AWARE SWIZZLE:
// bid = (G&7) + 8*qt + 64*(G>>3), G = p*16+b. All 48 blocks of batch b
// (6 pairs x 8 qt) land on XCD b&7 (round-robin XCD = bid%8); per-XCD
// working set (2 batches x 3 modalities x Q,K,V) ~4.6 MB ~ L2. Staging
// DMA becomes L2-hit; HBM fetch drops ~8x -> ~50 MB.
// ---------------------------------------------------------------------------
__global__ __launch_bounds__(256, 3) void attn_kernel(
    const unsigned short* __restrict__ Qbf,
    const unsigned short* __restrict__ Kbf,
    const unsigned short* __restrict__ Vt,
    unsigned short* __restrict__ part)
{
    __shared__ unsigned short Ks[2][4096];   // 8 slabs x [key 0..63][8elem]
    __shared__ unsigned short Vs[2][4096];   // 8 slabs x [d 0..63][8 keys]

    int bid = blockIdx.x;                    // 768 = 6 pairs * 16 b * 8 qt
    int cx  = bid & 7;
    int qt  = (bid >> 3) & 7;
    int gh  = bid >> 6;                      // [0,12)
    int G   = gh * 8 + cx;                   // [0,96) = p*16 + b
    int p   = G >> 4;
    int b   = G & 15;
    int i   = p >> 1, jj = p & 1;
    int j   = i + 1 + jj; if (j >= 3) j -= 3;

    int tid = threadIdx.x, wave = tid >> 6, lane = tid & 63;
    int lq = lane & 31, h = lane >> 5;

    const unsigned short* KgT = Kbf + ((size_t)j * B_DIM + b) * MBPLANE;
    const unsigned short* VgT = Vt  + ((size_t)j * B_DIM + b) * MBPLANE;
    const unsigned short* QgT = Qbf + ((size_t)i * B_DIM + b) * MBPLANE;

    // wave stages slabs {2w, 2w+1} of K and V; global side contiguous 1KB
    int c0 = wave * 2;
    auto stage = [&](int buf, int kt) {
        const unsigned short* gk = KgT + ((size_t)(kt * 8 + c0) * 64 + lane) * 8;
        const unsigned short* gv = VgT + ((size_t)(kt * 8 + c0) * 64 + lane) * 8;
        g2lds16(gk,       &Ks[buf][c0 * 512]);
        g2lds16(gk + 512, &Ks[buf][c0 * 512 + 512]);
        g2lds16(gv,       &Vs[buf][c0 * 512]);
        g2lds16(gv + 512, &Vs[buf][c0 * 512 + 512]);
    };

    // prologue: stage tiles 0 and 1
    stage(0, 0);
    stage(1, 1);

    // Q B-frags: wave owns 64 queries (q = qt*256 + wave*64 + qi*32 + lq)
    int g0 = qt * 4 + wave;
    bf16x8 qf[2][4];
    #pragma unroll
    for (int qi = 0; qi < 2; ++qi)
        #pragma unroll
        for (int kc = 0; kc < 4; ++kc)
            qf[qi][kc] = __builtin_bit_cast(bf16x8, *(const uint4*)&QgT[
                (size_t)(g0 * 2 + qi) * 2048 + (kc * 2 + h) * 256 + lq * 8]);

    // loop-invariant zero accumulator (C-operand; avoids per-stage v_movs)
    f32x16 ZERO;
    #pragma unroll
    for (int r = 0; r < 16; ++r) ZERO[r] = 0.f;

    f32x16 O[2][2];                          // [df][qi]
    #pragma unroll
    for (int r = 0; r < 16; ++r) { O[0][0][r] = 0.f; O[0][1][r] = 0.f; O[1][0][r] = 0.f; O[1][1][r] = 0.f; }
    f32x2 ls2[2]; ls2[0] = (f32x2)(0.f); ls2[1] = (f32x2)(0.f);

    // QK of one 32-key half-stage for both qi; interleaved independent chains
    auto QK = [&](const unsigned short* Kb, int kf, f32x16 stv[2]) {
        bf16x8 kfr[4];
        #pragma unroll
        for (int kc = 0; kc < 4; ++kc)
            kfr[kc] = __builtin_bit_cast(bf16x8,
                *(const uint4*)&Kb[(2 * kc + h) * 512 + (kf * 32 + lq) * 8]);
        stv[0] = __builtin_amdgcn_mfma_f32_32x32x16_bf16(kfr[0], qf[0][0], ZERO, 0, 0, 0);
        stv[1] = __builtin_amdgcn_mfma_f32_32x32x16_bf16(kfr[0], qf[1][0], ZERO, 0, 0, 0);
        #pragma unroll
        for (int kc = 1; kc < 4; ++kc) {
            stv[0] = __builtin_amdgcn_mfma_f32_32x32x16_bf16(kfr[kc], qf[0][kc], stv[0], 0, 0, 0);
            stv[1] = __builtin_amdgcn_mfma_f32_32x32x16_bf16(kfr[kc], qf[1][kc], stv[1], 0, 0, 0);
        }
    };

    // exp2 + lsum + pack scores into P-fragments for both qi
    auto EXPP = [&](const f32x16 stv[2], bf16x8 pf[2][2]) {
        #pragma unroll
        for (int qi = 0; qi < 2; ++qi) {
            unsigned pkk[4][2];
            #pragma unroll
            for (int s = 0; s < 4; ++s) {
                float e0 = __builtin_amdgcn_exp2f(stv[qi][4 * s + 0]);
                float e1 = __builtin_amdgcn_exp2f(stv[qi][4 * s + 1]);
                float e2 = __builtin_amdgcn_exp2f(stv[qi][4 * s + 2]);
                float e3 = __builtin_amdgcn_exp2f(stv[qi][4 * s + 3]);
                f32x2 p01; p01.x = e0; p01.y = e1;
                f32x2 p23; p23.x = e2; p23.y = e3;
                ls2[qi] += p01;              // v_pk_add_f32
                ls2[qi] += p23;
                pkk[s][0] = __builtin_amdgcn_perm(
                    __builtin_bit_cast(unsigned, e1), __builtin_bit_cast(unsigned, e0), 0x07060302u);
                pkk[s][1] = __builtin_amdgcn_perm(
                    __builtin_bit_cast(unsigned, e3), __builtin_bit_cast(unsigned, e2), 0x07060302u);
            }
            #pragma unroll
            for (int c = 0; c < 2; ++c) {
                u32x2 rr0 = half_swap(pkk[2 * c][0], pkk[2 * c + 1][0]);
                u32x2 rr1 = half_swap(pkk[2 * c][1], pkk[2 * c + 1][1]);
                uint4 t; t.x = rr0.x; t.y = rr1.x; t.z = rr0.y; t.w = rr1.y;
                pf[qi][c] = __builtin_bit_cast(bf16x8, t);
            }
        }
    };

    // PV of one half-stage: 4 shared vfr reads feed both qi accumulators
    auto PV = [&](const bf16x8 pf[2][2], const unsigned short* Vb, int kfp) {
        #pragma unroll
        for (int c = 0; c < 2; ++c) {
            int kcpv = 2 * kfp + c;
            bf16x8 vfr0 = __builtin_bit_cast(bf16x8,
                *(const uint4*)&Vb[(2 * kcpv + h) * 512 + lq * 8]);
            bf16x8 vfr1 = __builtin_bit_cast(bf16x8,
                *(const uint4*)&Vb[(2 * kcpv + h) * 512 + (32 + lq) * 8]);
            O[0][0] = __builtin_amdgcn_mfma_f32_32x32x16_bf16(vfr0, pf[0][c], O[0][0], 0, 0, 0);
            O[0][1] = __builtin_amdgcn_mfma_f32_32x32x16_bf16(vfr0, pf[1][c], O[0][1], 0, 0, 0);
            O[1][0] = __builtin_amdgcn_mfma_f32_32x32x16_bf16(vfr1, pf[0][c], O[1][0], 0, 0, 0);
            O[1][1] = __builtin_amdgcn_mfma_f32_32x32x16_bf16(vfr1, pf[1][c], O[1][1], 0, 0, 0);
        }
    };

    __syncthreads();    // publishes tiles 0,1

    // prologue compute: stage 0 (tile 0 kf0) and start of stage 1
    f32x16 st[2];
    QK(Ks[0], 0, st);
    {
        bf16x8 pfA[2][2];
        EXPP(st, pfA);                       // stage 0
        QK(Ks[0], 1, st);                    // stage 1
        PV(pfA, Vs[0], 0);                   // stage 0
    }

    for (int kt = 1; kt < 32; ++kt) {
        {
            bf16x8 pfB[2][2];
            EXPP(st, pfB);                   // stage 2kt-1 (tile kt-1, kf1)
            PV(pfB, Vs[(kt - 1) & 1], 1);    // last read of tile kt-1 V
        }
        __syncthreads();                     // publish tile kt; tile kt-1 bufs free
        if (kt < 31) stage((kt + 1) & 1, kt + 1);
        QK(Ks[kt & 1], 0, st);               // stage 2kt
        {
            bf16x8 pfC[2][2];
            EXPP(st, pfC);                   // stage 2kt
            QK(Ks[kt & 1], 1, st);           // stage 2kt+1
            PV(pfC, Vs[kt & 1], 0);          // stage 2kt
        }
    }

    // drain: stage 63 (tile 31, kf1, buf 1)
    {
        bf16x8 pfD[2][2];
        EXPP(st, pfD);
        PV(pfD, Vs[1], 1);
    }

    // epilogue: normalize, half-swap to row layout, store bf16 partial rows
    #pragma unroll
    for (int qi = 0; qi < 2; ++qi) {
        float l = ls2[qi].x + ls2[qi].y;
        l += __shfl_xor(l, 32);
        float inv = 1.0f / l;
        #pragma unroll
        for (int r = 0; r < 16; ++r) { O[0][qi][r] *= inv; O[1][qi][r] *= inv; }

        unsigned short* dst = part + ((size_t)jj * 3 + i) * PLANE
            + (size_t)(b * N_DIM + qt * 256 + wave * 64 + qi * 32 + lq) * 64 + h * 32;
        #pragma unroll
        for (int s = 0; s < 4; ++s) {
            unsigned t00 = pk_rne(O[0][qi][4 * s], O[0][qi][4 * s + 1]);
            unsigned t01 = pk_rne(O[0][qi][4 * s + 2], O[0][qi][4 * s + 3]);
            unsigned t10 = pk_rne(O[1][qi][4 * s], O[1][qi][4 * s + 1]);
            unsigned t11 = pk_rne(O[1][qi][4 * s + 2], O[1][qi][4 * s + 3]);
            u32x2 a = half_swap(t00, t10);
            u32x2 c = half_swap(t01, t11);
            uint4 w; w.x = a.x; w.y = c.x; w.z = a.y; w.w = c.y;
            *(uint4*)&dst[s * 8] = w;
        }
    }
}

// ---------------------------------------------------------------------------
// reduce: out = (1/3) * sum of 6 bf16 partial planes
// ---------------------------------------------------------------------------
__global__ __launch_bounds__(256) void reduce_kernel(
    const unsigned short* __restrict__ part, float* __restrict__ out)
{
    size_t e = ((size_t)blockIdx.x * 256 + threadIdx.x) * 4;
    float a0 = 0.f, a1 = 0.f, a2 = 0.f, a3 = 0.f;
    #pragma unroll
    for (int q = 0; q < 6; ++q) {
        const unsigned short* pp = part + (size_t)q * PLANE + e;
        unsigned u0 = *(const unsigned*)&pp[0];
        unsigned u1 = *(const unsigned*)&pp[2];
        a0 += __builtin_bit_cast(float, u0 << 16);
        a1 += __builtin_bit_cast(float, u0 & 0xffff0000u);
        a2 += __builtin_bit_cast(float, u1 << 16);
        a3 += __builtin_bit_cast(float, u1 & 0xffff0000u);
    }
    f32x4 v;
    v.x = a0 * (1.0f / 3.0f); v.y = a1 * (1.0f / 3.0f);
    v.z = a2 * (1.0f / 3.0f); v.w = a3 * (1.0f / 3.0f);
    *(f32x4*)&out[e] = v;
}

extern "C" void kernel_launch(void* const* d_in, const int* in_sizes, int n_in,
                              void* d_out, int out_size, void* d_ws, size_t ws_size,
                              hipStream_t stream)
{
    const float* x0 = (const float*)d_in[0];
    const float* x1 = (const float*)d_in[1];
    const float* x2 = (const float*)d_in[2];
    const float* w0 = (const float*)d_in[3];
    const float* w1 = (const float*)d_in[4];
    const float* w2 = (const float*)d_in[5];
    float* out = (float*)d_out;

    size_t nElem = (size_t)3 * BN * 64;
    unsigned short* Qbf = (unsigned short*)d_ws;
    unsigned short* Kbf = Qbf + nElem;
    unsigned short* Vt  = Kbf + nElem;
    unsigned short* part = Vt + nElem;            // 6 planes * BN*64 bf16
    unsigned short* wfrag = part + 6 * PLANE;     // 48 KB of W fragments

    hipLaunchKernelGGL(wprep_kernel, dim3(3), dim3(64), 0, stream,
                       w0, w1, w2, wfrag);
    hipLaunchKernelGGL(prep_kernel, dim3(3 * (BN / 128)), dim3(256), 0, stream,
                       x0, x1, x2, wfrag, Qbf, Kbf, Vt);
    hipLaunchKernelGGL(attn_kernel, dim3(6 * B_DIM * (N_DIM / 256)), dim3(256), 0, stream,
                       Qbf, Kbf, Vt, part);
    hipLaunchKernelGGL(reduce_kernel, dim3((BN * 64 / 4) / 256), dim3(256), 0, stream,
                       part, out);
}